// Round 3
// baseline (343.291 us; speedup 1.0000x reference)
//
#include <hip/hip_runtime.h>
#include <cstdint>
#include <cstddef>

#define D_     256
#define TWO_D  512
#define R_     16
#define N0_    8192
#define L_     6
#define NL_    8192
#define B_     512
#define TOTAL_ (N0_ + L_*NL_)

#define MT      32          // nodes (M) per layer block
#define XPITCH  520         // bf16 elems per X row (512 + 8 pad)
#define HPITCH  264         // bf16 elems per H row (256 + 8 pad)
#define OPITCH  264         // out-stage pitch (reuses X buffer)
#define GRID_   256
#define NBAR    8

using short8 = __attribute__((ext_vector_type(8))) short;   // 8 bf16 (4 VGPRs)
using f32x4  = __attribute__((ext_vector_type(4))) float;   // 4 fp32 acc

__device__ __forceinline__ unsigned short f2bf(float f) {
    union { float f; unsigned u; } v; v.f = f;
    unsigned u = v.u;
    return (unsigned short)((u + 0x7FFFu + ((u >> 16) & 1u)) >> 16);  // RNE
}
__device__ __forceinline__ float bf2f(unsigned short h) {
    union { unsigned u; float f; } v; v.u = ((unsigned)h) << 16;
    return v.f;
}
__device__ __forceinline__ float softplus_f(float x) {
    return fmaxf(x, 0.0f) + log1pf(expf(-fabsf(x)));
}

// Device-scope single-use grid barrier (slot idx zeroed by prep kernel).
// All 256 blocks are resident (capacity 2 blocks/CU) -> deadlock-free.
__device__ __forceinline__ void grid_barrier(unsigned* bar, int idx) {
    __syncthreads();
    if (threadIdx.x == 0) {
        __threadfence();                       // release: drain our writes to L2->L3
        atomicAdd(&bar[idx], 1u);              // device-scope
        while (__hip_atomic_load(&bar[idx], __ATOMIC_RELAXED,
                                 __HIP_MEMORY_SCOPE_AGENT) < GRID_) {
            __builtin_amdgcn_s_sleep(2);
        }
        __threadfence();                       // acquire: invalidate L1/L2
    }
    __syncthreads();
}

// ---------------------------------------------------------------- prep ----
// in: [r][K][N] fp32 -> out: [r][N][K] bf16 (64x64 tiles via LDS).
// Block 0 also zeroes the barrier slots + accum (idempotent, runs twice).
__global__ void transpose_w_k(const float* __restrict__ in,
                              unsigned short* __restrict__ out,
                              int K, int N, unsigned* __restrict__ bar,
                              float* __restrict__ accum) {
    if (blockIdx.x == 0 && threadIdx.x < NBAR) {
        bar[threadIdx.x] = 0u;
        accum[threadIdx.x] = 0.0f;
    }
    __shared__ unsigned short tile[64][65];
    int ktiles = K >> 6, ntiles = N >> 6;
    int tilesPer = ktiles * ntiles;
    int r  = blockIdx.x / tilesPer;
    int rm = blockIdx.x % tilesPer;
    int kt = rm / ntiles, nt = rm % ntiles;
    int t = threadIdx.x;
    const float* src = in + (size_t)r * K * N + (size_t)(kt * 64) * N + nt * 64;
    int c4 = t & 15, r0 = t >> 4;
    #pragma unroll
    for (int p = 0; p < 4; ++p) {
        int row = r0 + p * 16;
        float4 v = *(const float4*)(src + (size_t)row * N + c4 * 4);
        tile[row][c4 * 4 + 0] = f2bf(v.x);
        tile[row][c4 * 4 + 1] = f2bf(v.y);
        tile[row][c4 * 4 + 2] = f2bf(v.z);
        tile[row][c4 * 4 + 3] = f2bf(v.w);
    }
    __syncthreads();
    unsigned short* dst = out + ((size_t)r * N + nt * 64) * K + kt * 64;
    #pragma unroll
    for (int p = 0; p < 16; ++p) {
        int e = p * 256 + t;
        int n = e >> 6, k = e & 63;
        dst[(size_t)n * K + k] = tile[k][n];
    }
}

// ------------------------------------------------------- fused persistent --
// 256 blocks x 512 threads, 1 block/CU-slot guaranteed resident.
// Phases: init-gather | 6x (gather -> GEMM1 -> relu -> GEMM2 -> store) | eval.
// Rule<->XCD swizzle keeps each XCD on 2 rules (768 KB weights, L2-resident
// across ALL layers in this single dispatch).
__global__ __launch_bounds__(512, 2)
void fused_persistent_k(const int* __restrict__ thax,
                        const float* __restrict__ table,
                        unsigned short* __restrict__ storeb,
                        const int* __restrict__ par_all,   // [L][NL][2]
                        const unsigned short* __restrict__ w1t,  // [R][256][512]
                        const unsigned short* __restrict__ w2t,  // [R][256][256]
                        const float* __restrict__ b1,
                        const float* __restrict__ b2,
                        const float* __restrict__ eval_w,
                        const float* __restrict__ eval_b,
                        const float* __restrict__ pos_vals,
                        const float* __restrict__ neg_vals,
                        const float* __restrict__ pos_weight,
                        float* __restrict__ accum,
                        unsigned* __restrict__ bar,
                        float* __restrict__ out) {
    __shared__ unsigned short X[MT * XPITCH];   // 33280 B (also out-stage)
    __shared__ unsigned short H[MT * HPITCH];   // 16896 B
    __shared__ float sh[8];

    int bid = blockIdx.x;
    int tid = threadIdx.x;
    int r   = (bid & 7) | (((bid >> 3) & 1) << 3);   // XCD-local rule
    int mt  = bid >> 4;
    int nodeInLayer0 = r * B_ + mt * MT;

    int w    = tid >> 6;        // wave 0..7 -> n-slice base w*32
    int lane = tid & 63;
    int q    = lane >> 4;
    int ml   = lane & 15;
    int nb   = w * 32;

    const unsigned short* w1r = w1t + (size_t)r * D_ * TWO_D;
    const unsigned short* w2r = w2t + (size_t)r * D_ * D_;

    // ---- phase 0: init gather (rows [bid*32, bid*32+32) of storeb) ----
    {
        int row0 = bid * 32;
        #pragma unroll
        for (int it = 0; it < 4; ++it) {
            int e   = it * 512 + tid;          // 0..2047
            int row = row0 + (e >> 6);
            int c   = (e & 63) * 4;
            int t   = thax[row];
            float4 v = *(const float4*)(table + (size_t)t * D_ + c);
            ushort4 o;
            o.x = f2bf(v.x); o.y = f2bf(v.y); o.z = f2bf(v.z); o.w = f2bf(v.w);
            *(ushort4*)(storeb + (size_t)row * D_ + c) = o;
        }
    }
    grid_barrier(bar, 0);

    // ---- phases 1..6: layers ----
    for (int l = 0; l < L_; ++l) {
        const int* par = par_all + (size_t)l * NL_ * 2;

        // gather parents -> X
        int pidx[4];
        #pragma unroll
        for (int it = 0; it < 4; ++it) {
            int c = it * 512 + tid;
            pidx[it] = par[(nodeInLayer0 + (c >> 6)) * 2 + ((c & 63) >> 5)];
        }
        #pragma unroll
        for (int it = 0; it < 4; ++it) {
            int c   = it * 512 + tid;
            int m   = c >> 6;
            int rem = c & 63;
            int j   = rem >> 5;
            int c16 = rem & 31;
            uint4 v = *((const uint4*)(storeb + (size_t)pidx[it] * D_) + c16);
            *((uint4*)(&X[m * XPITCH + j * D_ + c16 * 8])) = v;
        }
        __syncthreads();

        // GEMM1: [32 x 512] @ [512 x 256] -> H, relu(.+b1)
        f32x4 acc[2][2] = {};
        #pragma unroll
        for (int ks = 0; ks < 16; ++ks) {
            int k0 = ks * 32 + q * 8;
            short8 a0 = *(const short8*)(&X[(0 * 16 + ml) * XPITCH + k0]);
            short8 a1 = *(const short8*)(&X[(1 * 16 + ml) * XPITCH + k0]);
            #pragma unroll
            for (int ni = 0; ni < 2; ++ni) {
                int n = nb + ni * 16 + ml;
                short8 b = *(const short8*)(&w1r[(size_t)n * TWO_D + k0]);
                acc[0][ni] = __builtin_amdgcn_mfma_f32_16x16x32_bf16(a0, b, acc[0][ni], 0, 0, 0);
                acc[1][ni] = __builtin_amdgcn_mfma_f32_16x16x32_bf16(a1, b, acc[1][ni], 0, 0, 0);
            }
        }
        #pragma unroll
        for (int ni = 0; ni < 2; ++ni) {
            int n = nb + ni * 16 + ml;
            float bias = b1[r * D_ + n];
            #pragma unroll
            for (int mi = 0; mi < 2; ++mi)
                #pragma unroll
                for (int v = 0; v < 4; ++v) {
                    int row = mi * 16 + q * 4 + v;   // C/D: row = quad*4+reg
                    float x = acc[mi][ni][v] + bias;
                    H[row * HPITCH + n] = f2bf(x > 0.0f ? x : 0.0f);
                }
        }
        __syncthreads();

        // GEMM2: [32 x 256] @ [256 x 256] (+b2)
        f32x4 acc2[2][2] = {};
        #pragma unroll
        for (int ks = 0; ks < 8; ++ks) {
            int k0 = ks * 32 + q * 8;
            short8 a0 = *(const short8*)(&H[(0 * 16 + ml) * HPITCH + k0]);
            short8 a1 = *(const short8*)(&H[(1 * 16 + ml) * HPITCH + k0]);
            #pragma unroll
            for (int ni = 0; ni < 2; ++ni) {
                int n = nb + ni * 16 + ml;
                short8 b = *(const short8*)(&w2r[(size_t)n * D_ + k0]);
                acc2[0][ni] = __builtin_amdgcn_mfma_f32_16x16x32_bf16(a0, b, acc2[0][ni], 0, 0, 0);
                acc2[1][ni] = __builtin_amdgcn_mfma_f32_16x16x32_bf16(a1, b, acc2[1][ni], 0, 0, 0);
            }
        }
        __syncthreads();        // X free; reuse as out-stage [32][OPITCH]
        #pragma unroll
        for (int ni = 0; ni < 2; ++ni) {
            int n = nb + ni * 16 + ml;
            float bias = b2[r * D_ + n];
            #pragma unroll
            for (int mi = 0; mi < 2; ++mi)
                #pragma unroll
                for (int v = 0; v < 4; ++v) {
                    int row = mi * 16 + q * 4 + v;
                    float x = acc2[mi][ni][v] + bias;
                    X[row * OPITCH + n] = f2bf(x);
                }
        }
        __syncthreads();
        // coalesced store: 32 rows x 512 B
        size_t outBase = (size_t)(N0_ + l * NL_ + nodeInLayer0);
        #pragma unroll
        for (int it = 0; it < 2; ++it) {
            int c   = it * 512 + tid;
            int m   = c >> 5;
            int c16 = c & 31;
            uint4 v = *((const uint4*)(&X[m * OPITCH]) + c16);
            *((uint4*)(storeb + (outBase + m) * D_) + c16) = v;
        }
        grid_barrier(bar, 1 + l);
    }

    // ---- phase 7: eval ----
    {
        int wid = bid * 8 + w;
        const int nw = GRID_ * 8;
        float ew0 = eval_w[lane * 4 + 0], ew1 = eval_w[lane * 4 + 1];
        float ew2 = eval_w[lane * 4 + 2], ew3 = eval_w[lane * 4 + 3];
        float pw = pos_weight[0], eb = eval_b[0];
        float loss = 0, posTot = 0, negTot = 0, posOK = 0, negOK = 0;
        for (int node = wid; node < TOTAL_; node += nw) {
            ushort4 v = *(const ushort4*)(storeb + (size_t)node * D_ + lane * 4);
            float s = bf2f(v.x) * ew0 + bf2f(v.y) * ew1 + bf2f(v.z) * ew2 + bf2f(v.w) * ew3;
            #pragma unroll
            for (int off = 32; off > 0; off >>= 1) s += __shfl_down(s, off);
            if (lane == 0) {
                float x   = s + eb;
                float pos = pos_vals[node], neg = neg_vals[node];
                float tot = pos + neg;
                if (tot > 0.0f) {
                    float tgt = pos / fmaxf(tot, 1e-9f);
                    loss += tot * (pw * tgt * softplus_f(-x) + (1.0f - tgt) * softplus_f(x));
                    posTot += pos; negTot += neg;
                    if (x >= 0.0f) posOK += pos; else negOK += neg;
                }
            }
        }
        if (tid == 0) { for (int i = 0; i < 5; ++i) sh[i] = 0.0f; }
        __syncthreads();
        if (lane == 0) {
            atomicAdd(&sh[0], loss); atomicAdd(&sh[1], posTot); atomicAdd(&sh[2], negTot);
            atomicAdd(&sh[3], posOK); atomicAdd(&sh[4], negOK);
        }
        __syncthreads();
        if (tid < 5) atomicAdd(&accum[tid], sh[tid]);
    }
    grid_barrier(bar, 7);

    // ---- finalize (block 0) ----
    if (bid == 0 && tid == 0) {
        float loss = accum[0], posTot = accum[1], negTot = accum[2];
        float posOK = accum[3], negOK = accum[4];
        out[0] = loss;
        out[1] = (posTot > 0.0f) ? posOK / fmaxf(posTot, 1e-9f) : 1.0f;
        out[2] = (negTot > 0.0f) ? negOK / fmaxf(negTot, 1e-9f) : 1.0f;
    }
}

// ---------------------------------------------------------------- launch ---
extern "C" void kernel_launch(void* const* d_in, const int* in_sizes, int n_in,
                              void* d_out, int out_size, void* d_ws, size_t ws_size,
                              hipStream_t stream) {
    const int*   thax       = (const int*)  d_in[0];
    const int*   par        = (const int*)  d_in[1];
    const float* pos_vals   = (const float*)d_in[2];
    const float* neg_vals   = (const float*)d_in[3];
    const float* init_table = (const float*)d_in[4];
    const float* W1         = (const float*)d_in[5];
    const float* b1         = (const float*)d_in[6];
    const float* W2         = (const float*)d_in[7];
    const float* b2         = (const float*)d_in[8];
    const float* eval_w     = (const float*)d_in[9];
    const float* eval_b     = (const float*)d_in[10];
    const float* pos_weight = (const float*)d_in[11];
    float* out = (float*)d_out;

    char* ws = (char*)d_ws;
    unsigned short* w1t    = (unsigned short*)(ws);                            // 4 MB
    unsigned short* w2t    = (unsigned short*)(ws + (size_t)4  * 1024 * 1024); // 2 MB
    unsigned short* storeb = (unsigned short*)(ws + (size_t)6  * 1024 * 1024); // 28 MB
    float*          accum  = (float*)(ws + (size_t)6 * 1024 * 1024 +
                                      (size_t)TOTAL_ * D_ * 2);
    unsigned*       bar    = (unsigned*)(accum + 16);

    hipLaunchKernelGGL(transpose_w_k, dim3(R_ * 8 * 4), dim3(256), 0, stream,
                       W1, w1t, TWO_D, D_, bar, accum);
    hipLaunchKernelGGL(transpose_w_k, dim3(R_ * 4 * 4), dim3(256), 0, stream,
                       W2, w2t, D_, D_, bar, accum);
    hipLaunchKernelGGL(fused_persistent_k, dim3(GRID_), dim3(512), 0, stream,
                       thax, init_table, storeb, par, w1t, w2t, b1, b2,
                       eval_w, eval_b, pos_vals, neg_vals, pos_weight,
                       accum, bar, out);
}

// Round 4
// 239.374 us; speedup vs baseline: 1.4341x; 1.4341x over previous
//
#include <hip/hip_runtime.h>
#include <cstdint>
#include <cstddef>

#define D_     256
#define TWO_D  512
#define R_     16
#define N0_    8192
#define L_     6
#define NL_    8192
#define B_     512
#define TOTAL_ (N0_ + L_*NL_)

#define MT      32          // nodes (M) per layer block
#define XPITCH  520         // bf16 elems per X row (512 + 8 pad; 4-bank row stride -> conflict-free b128)
#define HPITCH  264         // bf16 elems per H row (256 + 8 pad)
#define OPITCH  264         // out-stage pitch (reuses X buffer)

using short8 = __attribute__((ext_vector_type(8))) short;   // 8 bf16 (4 VGPRs)
using f32x4  = __attribute__((ext_vector_type(4))) float;   // 4 fp32 acc

__device__ __forceinline__ unsigned short f2bf(float f) {
    union { float f; unsigned u; } v; v.f = f;
    unsigned u = v.u;
    return (unsigned short)((u + 0x7FFFu + ((u >> 16) & 1u)) >> 16);  // RNE
}
__device__ __forceinline__ float bf2f(unsigned short h) {
    union { unsigned u; float f; } v; v.u = ((unsigned)h) << 16;
    return v.f;
}
__device__ __forceinline__ float softplus_f(float x) {
    return fmaxf(x, 0.0f) + log1pf(expf(-fabsf(x)));
}

// async global->LDS, 16B per lane; LDS dest = wave-uniform base + lane*16
__device__ __forceinline__ void stage16(const unsigned short* g, unsigned short* l) {
    __builtin_amdgcn_global_load_lds((const unsigned int*)g, (unsigned int*)l, 16, 0, 0);
}

// ---------------------------------------------------------------- prep ----
// in: [r][K][N] fp32 -> out: [r][N][K] bf16 (64x64 tiles via LDS)
__global__ void transpose_w_k(const float* __restrict__ in,
                              unsigned short* __restrict__ out,
                              int K, int N) {
    __shared__ unsigned short tile[64][65];
    int ktiles = K >> 6, ntiles = N >> 6;
    int tilesPer = ktiles * ntiles;
    int r  = blockIdx.x / tilesPer;
    int rm = blockIdx.x % tilesPer;
    int kt = rm / ntiles, nt = rm % ntiles;
    int t = threadIdx.x;
    const float* src = in + (size_t)r * K * N + (size_t)(kt * 64) * N + nt * 64;
    int c4 = t & 15, r0 = t >> 4;
    #pragma unroll
    for (int p = 0; p < 4; ++p) {
        int row = r0 + p * 16;
        float4 v = *(const float4*)(src + (size_t)row * N + c4 * 4);
        tile[row][c4 * 4 + 0] = f2bf(v.x);
        tile[row][c4 * 4 + 1] = f2bf(v.y);
        tile[row][c4 * 4 + 2] = f2bf(v.z);
        tile[row][c4 * 4 + 3] = f2bf(v.w);
    }
    __syncthreads();
    unsigned short* dst = out + ((size_t)r * N + nt * 64) * K + kt * 64;
    #pragma unroll
    for (int p = 0; p < 16; ++p) {
        int e = p * 256 + t;
        int n = e >> 6, k = e & 63;
        dst[(size_t)n * K + k] = tile[k][n];
    }
}

// storeb[:N0] = bf16(init_table[thax]); block 0 zeroes accum
__global__ void init_gather_k(const int* __restrict__ thax,
                              const float* __restrict__ table,
                              unsigned short* __restrict__ storeb,
                              float* __restrict__ accum) {
    if (blockIdx.x == 0 && threadIdx.x < 8) accum[threadIdx.x] = 0.0f;
    int gid = blockIdx.x * 256 + threadIdx.x;
    int row = gid >> 6;
    int c   = (gid & 63) * 4;
    int t   = thax[row];
    float4 v = *(const float4*)(table + (size_t)t * D_ + c);
    ushort4 o;
    o.x = f2bf(v.x); o.y = f2bf(v.y); o.z = f2bf(v.z); o.w = f2bf(v.w);
    *(ushort4*)(storeb + (size_t)row * D_ + c) = o;
}

// ---------------------------------------------------------------- layer ----
// 256 blocks x 512 threads (8 waves). Block = 32 nodes x full N=256 of one
// rule. Weights K-sliced (256n x 32k = 16 KB) double-buffered in LDS via
// global_load_lds. W staged layout: chunk c (=q'*256+n) at offset c*16B ->
// b-frag read (q*256+n)*16B is conflict-free. Rule<->XCD swizzle: 2 rules/XCD.
__global__ __launch_bounds__(512, 2)
void layer_k(unsigned short* __restrict__ storeb,
             const int* __restrict__ par,              // this layer: [NL][2]
             const unsigned short* __restrict__ w1t,   // [R][256][512] bf16
             const unsigned short* __restrict__ w2t,   // [R][256][256] bf16
             const float* __restrict__ b1,
             const float* __restrict__ b2,
             int layer) {
    __shared__ unsigned short X[MT * XPITCH];     // 33280 B (also out-stage)
    __shared__ unsigned short WB[2 * 4096 * 2];   // 2 x 16 KB weight slices
    __shared__ unsigned short H[MT * HPITCH];     // 16896 B

    int bid = blockIdx.x;
    int r   = (bid & 7) | (((bid >> 3) & 1) << 3);   // XCD-local rule
    int mt  = bid >> 4;
    int tid = threadIdx.x;
    int nodeInLayer0 = r * B_ + mt * MT;

    int w    = tid >> 6;        // wave 0..7 -> n-slice base w*32
    int lane = tid & 63;
    int q    = lane >> 4;
    int ml   = lane & 15;
    int nb   = w * 32;

    const unsigned short* w1r = w1t + (size_t)r * D_ * TWO_D;
    const unsigned short* w2r = w2t + (size_t)r * D_ * D_;

    // stage W1 slice 0 (async, ahead of gather)
    #pragma unroll
    for (int i = 0; i < 2; ++i) {
        int c  = i * 512 + tid;
        int qq = c >> 8, n = c & 255;
        stage16(w1r + (size_t)n * TWO_D + qq * 8,
                WB + (size_t)(i * 512 + w * 64) * 8);
    }

    // gather parents -> X
    int pidx[4];
    #pragma unroll
    for (int it = 0; it < 4; ++it) {
        int c = it * 512 + tid;
        pidx[it] = par[(nodeInLayer0 + (c >> 6)) * 2 + ((c & 63) >> 5)];
    }
    #pragma unroll
    for (int it = 0; it < 4; ++it) {
        int c   = it * 512 + tid;
        int m   = c >> 6;
        int rem = c & 63;
        int j   = rem >> 5;
        int c16 = rem & 31;
        uint4 v = *((const uint4*)(storeb + (size_t)pidx[it] * D_) + c16);
        *((uint4*)(&X[m * XPITCH + j * D_ + c16 * 8])) = v;
    }
    __syncthreads();    // X ready; W1 slice 0 landed (vmcnt drained)

    // ---- GEMM1: [32 x 512] @ W1T, K-steps of 32, dbuf staging ----
    f32x4 acc[2][2] = {};
    #pragma unroll
    for (int ks = 0; ks < 16; ++ks) {
        // stage next slice (W1 ks+1, or W2 slice 0 at the tail)
        if (ks < 15) {
            int k0 = (ks + 1) * 32;
            unsigned short* lb = WB + ((ks + 1) & 1) * 8192;
            #pragma unroll
            for (int i = 0; i < 2; ++i) {
                int c  = i * 512 + tid;
                int qq = c >> 8, n = c & 255;
                stage16(w1r + (size_t)n * TWO_D + k0 + qq * 8,
                        lb + (size_t)(i * 512 + w * 64) * 8);
            }
        } else {
            unsigned short* lb = WB;            // (16&1)==0
            #pragma unroll
            for (int i = 0; i < 2; ++i) {
                int c  = i * 512 + tid;
                int qq = c >> 8, n = c & 255;
                stage16(w2r + (size_t)n * D_ + qq * 8,
                        lb + (size_t)(i * 512 + w * 64) * 8);
            }
        }
        // compute from current slice
        const unsigned short* wb = WB + (ks & 1) * 8192;
        int k0 = ks * 32 + q * 8;
        short8 a0 = *(const short8*)(&X[(0 * 16 + ml) * XPITCH + k0]);
        short8 a1 = *(const short8*)(&X[(1 * 16 + ml) * XPITCH + k0]);
        #pragma unroll
        for (int ni = 0; ni < 2; ++ni) {
            short8 b = *(const short8*)(&wb[(size_t)(q * 256 + nb + ni * 16 + ml) * 8]);
            acc[0][ni] = __builtin_amdgcn_mfma_f32_16x16x32_bf16(a0, b, acc[0][ni], 0, 0, 0);
            acc[1][ni] = __builtin_amdgcn_mfma_f32_16x16x32_bf16(a1, b, acc[1][ni], 0, 0, 0);
        }
        if (ks == 15) {
            // bias + relu -> H (own acc only; before barrier)
            #pragma unroll
            for (int ni = 0; ni < 2; ++ni) {
                int n = nb + ni * 16 + ml;
                float bias = b1[r * D_ + n];
                #pragma unroll
                for (int mi = 0; mi < 2; ++mi)
                    #pragma unroll
                    for (int v = 0; v < 4; ++v) {
                        int row = mi * 16 + q * 4 + v;   // C/D: row = quad*4+reg
                        float x = acc[mi][ni][v] + bias;
                        H[row * HPITCH + n] = f2bf(x > 0.0f ? x : 0.0f);
                    }
            }
        }
        __syncthreads();
    }

    // ---- GEMM2: [32 x 256] @ W2T, K-steps of 32, dbuf staging ----
    f32x4 acc2[2][2] = {};
    #pragma unroll
    for (int ks = 0; ks < 8; ++ks) {
        if (ks < 7) {
            int k0 = (ks + 1) * 32;
            unsigned short* lb = WB + ((ks + 1) & 1) * 8192;
            #pragma unroll
            for (int i = 0; i < 2; ++i) {
                int c  = i * 512 + tid;
                int qq = c >> 8, n = c & 255;
                stage16(w2r + (size_t)n * D_ + k0 + qq * 8,
                        lb + (size_t)(i * 512 + w * 64) * 8);
            }
        }
        const unsigned short* wb = WB + (ks & 1) * 8192;
        int k0 = ks * 32 + q * 8;
        short8 a0 = *(const short8*)(&H[(0 * 16 + ml) * HPITCH + k0]);
        short8 a1 = *(const short8*)(&H[(1 * 16 + ml) * HPITCH + k0]);
        #pragma unroll
        for (int ni = 0; ni < 2; ++ni) {
            short8 b = *(const short8*)(&wb[(size_t)(q * 256 + nb + ni * 16 + ml) * 8]);
            acc2[0][ni] = __builtin_amdgcn_mfma_f32_16x16x32_bf16(a0, b, acc2[0][ni], 0, 0, 0);
            acc2[1][ni] = __builtin_amdgcn_mfma_f32_16x16x32_bf16(a1, b, acc2[1][ni], 0, 0, 0);
        }
        __syncthreads();
    }

    // X reads all done (GEMM1 finished) -> reuse X as out-stage [32][OPITCH]
    #pragma unroll
    for (int ni = 0; ni < 2; ++ni) {
        int n = nb + ni * 16 + ml;
        float bias = b2[r * D_ + n];
        #pragma unroll
        for (int mi = 0; mi < 2; ++mi)
            #pragma unroll
            for (int v = 0; v < 4; ++v) {
                int row = mi * 16 + q * 4 + v;
                float x = acc2[mi][ni][v] + bias;
                X[row * OPITCH + n] = f2bf(x);
            }
    }
    __syncthreads();
    size_t outBase = (size_t)(N0_ + layer * NL_ + nodeInLayer0);
    #pragma unroll
    for (int it = 0; it < 2; ++it) {
        int c   = it * 512 + tid;
        int m   = c >> 5;
        int c16 = c & 31;
        uint4 v = *((const uint4*)(&X[m * OPITCH]) + c16);
        *((uint4*)(storeb + (outBase + m) * D_) + c16) = v;
    }
}

// ---------------------------------------------------------------- eval ----
__global__ void eval_k(const unsigned short* __restrict__ storeb,
                       const float* __restrict__ eval_w,
                       const float* __restrict__ eval_b,
                       const float* __restrict__ pos_vals,
                       const float* __restrict__ neg_vals,
                       const float* __restrict__ pos_weight,
                       float* __restrict__ accum) {
    int lane = threadIdx.x & 63;
    int wid  = blockIdx.x * (blockDim.x >> 6) + (threadIdx.x >> 6);
    int nw   = gridDim.x * (blockDim.x >> 6);
    float ew0 = eval_w[lane * 4 + 0], ew1 = eval_w[lane * 4 + 1];
    float ew2 = eval_w[lane * 4 + 2], ew3 = eval_w[lane * 4 + 3];
    float pw = pos_weight[0], eb = eval_b[0];
    float loss = 0, posTot = 0, negTot = 0, posOK = 0, negOK = 0;

    for (int node = wid; node < TOTAL_; node += nw) {
        ushort4 v = *(const ushort4*)(storeb + (size_t)node * D_ + lane * 4);
        float s = bf2f(v.x) * ew0 + bf2f(v.y) * ew1 + bf2f(v.z) * ew2 + bf2f(v.w) * ew3;
        #pragma unroll
        for (int off = 32; off > 0; off >>= 1) s += __shfl_down(s, off);
        if (lane == 0) {
            float x   = s + eb;
            float pos = pos_vals[node], neg = neg_vals[node];
            float tot = pos + neg;
            if (tot > 0.0f) {
                float tgt = pos / fmaxf(tot, 1e-9f);
                loss += tot * (pw * tgt * softplus_f(-x) + (1.0f - tgt) * softplus_f(x));
                posTot += pos; negTot += neg;
                if (x >= 0.0f) posOK += pos; else negOK += neg;
            }
        }
    }
    __shared__ float sh[5];
    if (threadIdx.x == 0) { for (int i = 0; i < 5; ++i) sh[i] = 0.0f; }
    __syncthreads();
    if (lane == 0) {
        atomicAdd(&sh[0], loss); atomicAdd(&sh[1], posTot); atomicAdd(&sh[2], negTot);
        atomicAdd(&sh[3], posOK); atomicAdd(&sh[4], negOK);
    }
    __syncthreads();
    if (threadIdx.x < 5) atomicAdd(&accum[threadIdx.x], sh[threadIdx.x]);
}

__global__ void finalize_k(const float* __restrict__ accum, float* __restrict__ out) {
    if (threadIdx.x == 0) {
        float loss = accum[0], posTot = accum[1], negTot = accum[2];
        float posOK = accum[3], negOK = accum[4];
        out[0] = loss;
        out[1] = (posTot > 0.0f) ? posOK / fmaxf(posTot, 1e-9f) : 1.0f;
        out[2] = (negTot > 0.0f) ? negOK / fmaxf(negTot, 1e-9f) : 1.0f;
    }
}

// ---------------------------------------------------------------- launch ---
extern "C" void kernel_launch(void* const* d_in, const int* in_sizes, int n_in,
                              void* d_out, int out_size, void* d_ws, size_t ws_size,
                              hipStream_t stream) {
    const int*   thax       = (const int*)  d_in[0];
    const int*   par        = (const int*)  d_in[1];
    const float* pos_vals   = (const float*)d_in[2];
    const float* neg_vals   = (const float*)d_in[3];
    const float* init_table = (const float*)d_in[4];
    const float* W1         = (const float*)d_in[5];
    const float* b1         = (const float*)d_in[6];
    const float* W2         = (const float*)d_in[7];
    const float* b2         = (const float*)d_in[8];
    const float* eval_w     = (const float*)d_in[9];
    const float* eval_b     = (const float*)d_in[10];
    const float* pos_weight = (const float*)d_in[11];
    float* out = (float*)d_out;

    char* ws = (char*)d_ws;
    unsigned short* w1t    = (unsigned short*)(ws);                            // 4 MB
    unsigned short* w2t    = (unsigned short*)(ws + (size_t)4  * 1024 * 1024); // 2 MB
    unsigned short* storeb = (unsigned short*)(ws + (size_t)6  * 1024 * 1024); // 28 MB
    float*          accum  = (float*)(ws + (size_t)6 * 1024 * 1024 +
                                      (size_t)TOTAL_ * D_ * 2);

    hipLaunchKernelGGL(transpose_w_k, dim3(R_ * 8 * 4), dim3(256), 0, stream,
                       W1, w1t, TWO_D, D_);
    hipLaunchKernelGGL(transpose_w_k, dim3(R_ * 4 * 4), dim3(256), 0, stream,
                       W2, w2t, D_, D_);
    hipLaunchKernelGGL(init_gather_k, dim3(N0_ * 64 / 256), dim3(256), 0, stream,
                       thax, init_table, storeb, accum);
    for (int l = 0; l < L_; ++l) {
        hipLaunchKernelGGL(layer_k, dim3(256), dim3(512), 0, stream,
                           storeb, par + (size_t)l * NL_ * 2, w1t, w2t, b1, b2, l);
    }
    hipLaunchKernelGGL(eval_k, dim3(512), dim3(256), 0, stream,
                       storeb, eval_w, eval_b, pos_vals, neg_vals, pos_weight, accum);
    hipLaunchKernelGGL(finalize_k, dim3(1), dim3(1), 0, stream, accum, out);
}